// Round 5
// baseline (950.226 us; speedup 1.0000x reference)
//
#include <hip/hip_runtime.h>

#define BB 16
#define CC 64
#define NN 65536
#define NBV 4
// primary (transposed) path: 256 blocks/batch x 4 waves
#define PNP 1024
#define PBP (BB * PNP)
// fallback (c-major, round-3 proven) path
#define FNP 512
#define FBP (BB * FNP)

// ws layout primary (fp32 elems):
//   score B*N | bval 2*PBP | bidx 2*PBP (int) | wpart B*256*64 | sspart PBP | rawbuf B*64 | x_t B*N*64
//
// Round-5 theory: read BW scales with resident waves x memory duty cycle.
// k_iter loses its argmax prologue (-> k_pick), LDS 38->18.8 KB, VGPR ~85 -> ~5 blk/CU.
// Transpose retiled to 64px x 64ch (17.4 KB LDS, tiny VGPR -> ~8 blk/CU).

// ---------- primary path ----------

// x [b][c][n] -> x_t [b][n][c]; 64px x 64ch tiles. Reads: 256B contiguous per channel row
// (4 rows per wave instr). Writes: 64B contiguous per thread, 4KB per wave. ~32 waves/CU.
__global__ __launch_bounds__(256)
void k_transpose(const float* __restrict__ x, float* __restrict__ xt) {
    int b = blockIdx.y;
    int px0 = blockIdx.x * 64;
    int t = threadIdx.x;
    __shared__ float lds[64][68];   // 68: 16B-aligned rows, modest read-back conflicts
    #pragma unroll
    for (int m = 0; m < 4; m++) {
        int f = t + m * 256;        // 1024 float4 = 64 rows x 16
        int row = f >> 4, jj = f & 15;
        float4 v = *(const float4*)(x + ((size_t)(b * 64 + row)) * NN + px0 + jj * 4);
        *(float4*)&lds[row][jj * 4] = v;
    }
    __syncthreads();
    int p = t >> 2, qc = t & 3;     // pixel p (0..63), channel-quarter qc
    float4 o[4];
    #pragma unroll
    for (int m = 0; m < 4; m++) {
        int c0 = qc * 16 + m * 4;
        o[m] = make_float4(lds[c0][p], lds[c0 + 1][p], lds[c0 + 2][p], lds[c0 + 3][p]);
    }
    float* dst = xt + ((size_t)b * NN + px0 + p) * 64 + qc * 16;
    #pragma unroll
    for (int m = 0; m < 4; m++) ((float4*)dst)[m] = o[m];
}

// Initial argmax over score_init + zero selectedPos. 256 blocks/batch, 1 px/thread.
// Tie rule everywhere: larger value wins; equal -> smaller index (np.argmax = first max).
__global__ __launch_bounds__(256)
void k_argmax1(const float* __restrict__ sc_in,
               float* __restrict__ bval, int* __restrict__ bidx,
               float* __restrict__ sel_out) {
    int b = blockIdx.y, blk = blockIdx.x, tid = threadIdx.x;
    int lane = tid & 63, wv = tid >> 6;
    int n0 = blk * 256 + tid;
    float v = sc_in[(size_t)b * NN + n0]; int vi = n0;
    sel_out[(size_t)b * NN + n0] = 0.f;
    #pragma unroll
    for (int off = 32; off >= 1; off >>= 1) {
        float ov = __shfl_down(v, off, 64); int oi = __shfl_down(vi, off, 64);
        if (ov > v || (ov == v && oi < vi)) { v = ov; vi = oi; }
    }
    if (lane == 0) { bval[b * PNP + blk * 4 + wv] = v; bidx[b * PNP + blk * 4 + wv] = vi; }
}

// Finalize argmax over 1024 partials + gather selected pixel's 64 channels (one 256B read).
// Removes this work from every k_iter block's critical path.
__global__ __launch_bounds__(256)
void k_pick(const float* __restrict__ xt, const float* __restrict__ bval,
            const int* __restrict__ bidx, float* __restrict__ rawbuf, int iter) {
    int b = blockIdx.x, tid = threadIdx.x;
    int rb = (iter & 1) * PBP;
    __shared__ float sv[256]; __shared__ int si[256];
    const float* bv = bval + rb + b * PNP;
    const int* bi = bidx + rb + b * PNP;
    float v = bv[tid]; int vi = bi[tid];
    #pragma unroll
    for (int s = 1; s < 4; s++) {
        float ov = bv[tid + 256 * s]; int oi = bi[tid + 256 * s];
        if (ov > v || (ov == v && oi < vi)) { v = ov; vi = oi; }
    }
    sv[tid] = v; si[tid] = vi;
    __syncthreads();
    for (int st = 128; st > 0; st >>= 1) {
        if (tid < st) {
            float ov = sv[tid + st]; int oi = si[tid + st];
            if (ov > sv[tid] || (ov == sv[tid] && oi < si[tid])) { sv[tid] = ov; si[tid] = oi; }
        }
        __syncthreads();
    }
    int ind = si[0];
    if (tid < 64) rawbuf[b * 64 + tid] = xt[((size_t)b * NN + ind) * 64 + tid];
}

// Transposed-layout iteration, occupancy-optimized. grid=(256,B), 256 thr, 1 px/thread.
// Phase A: 16 dwordx4 (two batches of 8), lane-local d2 -> sim; sim/score I/O + argmax.
// Phase B: re-read the block's 64KB footprint (L2/L3-hot) via laundered pointer so
// phase-A regs stay dead (VGPR ~85), reduce sim*x per 16-channel chunk via LDS tree.
__global__ __launch_bounds__(256)
void k_iter_t(const float* __restrict__ xt, const float* __restrict__ score_in,
              float* __restrict__ score_out,
              float* __restrict__ bval, int* __restrict__ bidx,
              float* __restrict__ wpart, float* __restrict__ sspart,
              float* __restrict__ sim_out, const float* __restrict__ rawbuf, int iter) {
    int b = blockIdx.y, blk = blockIdx.x, tid = threadIdx.x;
    int lane = tid & 63, wv = tid >> 6;
    __shared__ __align__(16) float raw_s[64];
    __shared__ float lacc[256][17];   // 17: conflict-free row writes, 2-way col reads
    __shared__ float lq[16][17];

    int wb = ((iter & 1) ^ 1) * PBP;
    if (tid < 64) raw_s[tid] = rawbuf[b * 64 + tid];
    __syncthreads();

    int n0 = blk * 256 + tid;
    const float4* xp = (const float4*)(xt + ((size_t)b * NN + n0) * 64);

    // phase A: d2 in two 8-float4 batches (bufA dies before bufB's use -> low peak VGPR)
    float4 bufA[8], bufB[8];
    #pragma unroll
    for (int j = 0; j < 8; j++) bufA[j] = xp[j];
    #pragma unroll
    for (int j = 0; j < 8; j++) bufB[j] = xp[8 + j];
    float d2 = 0.f;
    #pragma unroll
    for (int j = 0; j < 8; j++) {
        float4 r4 = *(const float4*)&raw_s[j * 4];
        float dx = bufA[j].x - r4.x, dy = bufA[j].y - r4.y;
        float dz = bufA[j].z - r4.z, dw = bufA[j].w - r4.w;
        d2 = fmaf(dx, dx, d2); d2 = fmaf(dy, dy, d2);
        d2 = fmaf(dz, dz, d2); d2 = fmaf(dw, dw, d2);
    }
    #pragma unroll
    for (int j = 0; j < 8; j++) {
        float4 r4 = *(const float4*)&raw_s[32 + j * 4];
        float dx = bufB[j].x - r4.x, dy = bufB[j].y - r4.y;
        float dz = bufB[j].z - r4.z, dw = bufB[j].w - r4.w;
        d2 = fmaf(dx, dx, d2); d2 = fmaf(dy, dy, d2);
        d2 = fmaf(dz, dz, d2); d2 = fmaf(dw, dw, d2);
    }
    float sim = expf(-sqrtf(fmaxf(d2, 1e-12f)) * 0.05f);

    const size_t sb = (size_t)b * NN;
    sim_out[((size_t)(b * NBV + iter)) * NN + n0] = sim;
    const bool upd = (iter < 3);
    float ss = sim, smax = -1e30f; int smaxi = n0;
    if (upd) {
        float nc = score_in[sb + n0] * (1.f - sim);
        score_out[sb + n0] = nc;
        smax = nc;
    }

    // phase B: reload footprint (L2-hot); laundered ptr prevents CSE keeping phase-A regs
    const float4* xp2 = xp;
    asm volatile("" : "+v"(xp2));
    __builtin_amdgcn_sched_barrier(0);
    float4 rl[16];
    #pragma unroll
    for (int j = 0; j < 16; j++) rl[j] = xp2[j];

    auto do_chunk = [&](int q, float4 w0, float4 w1, float4 w2, float4 w3) {
        lacc[tid][0]  = sim * w0.x; lacc[tid][1]  = sim * w0.y;
        lacc[tid][2]  = sim * w0.z; lacc[tid][3]  = sim * w0.w;
        lacc[tid][4]  = sim * w1.x; lacc[tid][5]  = sim * w1.y;
        lacc[tid][6]  = sim * w1.z; lacc[tid][7]  = sim * w1.w;
        lacc[tid][8]  = sim * w2.x; lacc[tid][9]  = sim * w2.y;
        lacc[tid][10] = sim * w2.z; lacc[tid][11] = sim * w2.w;
        lacc[tid][12] = sim * w3.x; lacc[tid][13] = sim * w3.y;
        lacc[tid][14] = sim * w3.z; lacc[tid][15] = sim * w3.w;
        __syncthreads();
        int cc = tid & 15, seg = tid >> 4;
        float s = 0.f;
        #pragma unroll
        for (int r = 0; r < 16; r++) s += lacc[seg * 16 + r][cc];
        lq[seg][cc] = s;
        __syncthreads();
        if (tid < 16) {
            float wsum = 0.f;
            #pragma unroll
            for (int s2 = 0; s2 < 16; s2++) wsum += lq[s2][tid];
            wpart[((size_t)b * 256 + blk) * 64 + q * 16 + tid] = wsum;
        }
        __syncthreads();
    };
    do_chunk(0, rl[0],  rl[1],  rl[2],  rl[3]);
    do_chunk(1, rl[4],  rl[5],  rl[6],  rl[7]);
    do_chunk(2, rl[8],  rl[9],  rl[10], rl[11]);
    do_chunk(3, rl[12], rl[13], rl[14], rl[15]);

    // wave reductions: sim-sum + fused stage-1 argmax of the NEW score
    #pragma unroll
    for (int off = 32; off >= 1; off >>= 1) ss += __shfl_down(ss, off, 64);
    if (lane == 0) sspart[b * PNP + blk * 4 + wv] = ss;
    if (upd) {
        float v = smax; int idx = smaxi;
        #pragma unroll
        for (int off = 32; off >= 1; off >>= 1) {
            float ov = __shfl_down(v, off, 64); int oi = __shfl_down(idx, off, 64);
            if (ov > v || (ov == v && oi < idx)) { v = ov; idx = oi; }
        }
        if (lane == 0) { bval[wb + b * PNP + blk * 4 + wv] = v; bidx[wb + b * PNP + blk * 4 + wv] = idx; }
    }
}

__global__ __launch_bounds__(256)
void k_fin(const float* __restrict__ wpart, const float* __restrict__ sspart,
           float* __restrict__ vec_out, int iter) {
    int b = blockIdx.x, tid = threadIdx.x;
    int c = tid & 63, q = tid >> 6;
    __shared__ float lw[4][64];
    __shared__ float lss[256];
    float s4 = 0.f;
    #pragma unroll
    for (int i = 0; i < 4; i++) s4 += sspart[b * PNP + i * 256 + tid];
    lss[tid] = s4;
    float w = 0.f;
    for (int i = 0; i < 64; i++) w += wpart[((size_t)b * 256 + q * 64 + i) * 64 + c];
    lw[q][c] = w;
    __syncthreads();
    for (int st = 128; st > 0; st >>= 1) {
        if (tid < st) lss[tid] += lss[tid + st];
        __syncthreads();
    }
    if (tid < 64) {
        float tot = (lw[0][tid] + lw[1][tid]) + (lw[2][tid] + lw[3][tid]);
        vec_out[(b * NBV + iter) * 64 + tid] = tot / lss[0];
    }
}

// ---------- fallback path (round-3 proven, used only if ws too small) ----------

__global__ __launch_bounds__(256)
void k_argmax1_fb(const float* __restrict__ sc_in,
                  float* __restrict__ bval, int* __restrict__ bidx,
                  float* __restrict__ sel_out) {
    int b = blockIdx.y, blk = blockIdx.x, tid = threadIdx.x;
    int lane = tid & 63, wv = tid >> 6;
    int n0 = blk * 512 + tid * 2;
    const float* s = sc_in + (size_t)b * NN;
    float v0 = s[n0], v1 = s[n0 + 1];
    float v = v0; int vi = n0;
    if (v1 > v) { v = v1; vi = n0 + 1; }
    sel_out[(size_t)b * NN + n0] = 0.f;
    sel_out[(size_t)b * NN + n0 + 1] = 0.f;
    #pragma unroll
    for (int off = 32; off >= 1; off >>= 1) {
        float ov = __shfl_down(v, off, 64); int oi = __shfl_down(vi, off, 64);
        if (ov > v || (ov == v && oi < vi)) { v = ov; vi = oi; }
    }
    if (lane == 0) { bval[b * FNP + blk * 4 + wv] = v; bidx[b * FNP + blk * 4 + wv] = vi; }
}

__global__ __launch_bounds__(256, 2)
void k_iter_fb(const float* __restrict__ x, const float* __restrict__ score_in,
               float* __restrict__ score_out,
               float* __restrict__ bval, int* __restrict__ bidx,
               float* __restrict__ wpart, float* __restrict__ sspart,
               float* __restrict__ sim_out, int iter) {
    int b = blockIdx.y, blk = blockIdx.x, tid = threadIdx.x;
    int lane = tid & 63, wv = tid >> 6;
    __shared__ float sv[256]; __shared__ int si[256];
    __shared__ float raw_s[64];
    int rb = (iter & 1) * FBP, wb = ((iter & 1) ^ 1) * FBP;
    {
        const float* bv = bval + rb + b * FNP;
        const int* bi = bidx + rb + b * FNP;
        float v = bv[tid]; int vi = bi[tid];
        float v2 = bv[tid + 256]; int vi2 = bi[tid + 256];
        if (v2 > v || (v2 == v && vi2 < vi)) { v = v2; vi = vi2; }
        sv[tid] = v; si[tid] = vi;
        __syncthreads();
        for (int st = 128; st > 0; st >>= 1) {
            if (tid < st) {
                float ov = sv[tid + st]; int oi = si[tid + st];
                if (ov > sv[tid] || (ov == sv[tid] && oi < si[tid])) { sv[tid] = ov; si[tid] = oi; }
            }
            __syncthreads();
        }
    }
    int ind = si[0];
    if (tid < 64) raw_s[tid] = x[((size_t)(b * 64 + tid)) * NN + ind];
    __syncthreads();
    int p = blk * 4 + wv;
    int n0 = blk * 512 + wv * 128 + lane * 2;
    const float* xb = x + (size_t)b * 64 * NN + n0;
    const size_t sb = (size_t)b * NN;
    const bool upd = (iter < 3);
    float2 sc = make_float2(0.f, 0.f);
    if (upd) sc = *(const float2*)(score_in + sb + n0);
    float2 xv[64];
    #pragma unroll
    for (int c = 0; c < 64; c++) xv[c] = *(const float2*)(xb + (size_t)c * NN);
    float d2x = 0.f, d2y = 0.f;
    #pragma unroll
    for (int c = 0; c < 64; c++) {
        float r = raw_s[c];
        float dx = xv[c].x - r, dy = xv[c].y - r;
        d2x = fmaf(dx, dx, d2x); d2y = fmaf(dy, dy, d2y);
    }
    float simx = expf(-sqrtf(fmaxf(d2x, 1e-12f)) * 0.05f);
    float simy = expf(-sqrtf(fmaxf(d2y, 1e-12f)) * 0.05f);
    *(float2*)(sim_out + ((size_t)(b * NBV + iter)) * NN + n0) = make_float2(simx, simy);
    float ss = simx + simy;
    float smax = -1e30f; int smaxi = 0x7fffffff;
    if (upd) {
        float ncx = sc.x * (1.f - simx), ncy = sc.y * (1.f - simy);
        *(float2*)(score_out + sb + n0) = make_float2(ncx, ncy);
        smax = ncx; smaxi = n0;
        if (ncy > smax) { smax = ncy; smaxi = n0 + 1; }
    }
    float accl[64];
    #pragma unroll
    for (int c = 0; c < 64; c++) accl[c] = fmaf(simx, xv[c].x, simy * xv[c].y);
    #pragma unroll
    for (int c = 0; c < 64; c++) {
        float v = accl[c];
        #pragma unroll
        for (int off = 32; off >= 1; off >>= 1) v += __shfl_down(v, off, 64);
        if (lane == 0) wpart[((size_t)b * FNP + p) * 64 + c] = v;
    }
    #pragma unroll
    for (int off = 32; off >= 1; off >>= 1) ss += __shfl_down(ss, off, 64);
    if (lane == 0) sspart[b * FNP + p] = ss;
    if (upd) {
        #pragma unroll
        for (int off = 32; off >= 1; off >>= 1) {
            float ov = __shfl_down(smax, off, 64); int oi = __shfl_down(smaxi, off, 64);
            if (ov > smax || (ov == smax && oi < smaxi)) { smax = ov; smaxi = oi; }
        }
        if (lane == 0) { bval[wb + b * FNP + p] = smax; bidx[wb + b * FNP + p] = smaxi; }
    }
}

__global__ __launch_bounds__(256)
void k_fin_fb(const float* __restrict__ wpart, const float* __restrict__ sspart,
              float* __restrict__ vec_out, int iter) {
    int b = blockIdx.x, tid = threadIdx.x;
    int c = tid & 63, q = tid >> 6;
    __shared__ float lw[4][64];
    __shared__ float lss[256];
    lss[tid] = sspart[b * FNP + 2 * tid] + sspart[b * FNP + 2 * tid + 1];
    float w = 0.f;
    for (int i = 0; i < 128; i++) w += wpart[((size_t)b * FNP + q * 128 + i) * 64 + c];
    lw[q][c] = w;
    __syncthreads();
    for (int st = 128; st > 0; st >>= 1) {
        if (tid < st) lss[tid] += lss[tid + st];
        __syncthreads();
    }
    if (tid < 64) {
        float tot = (lw[0][tid] + lw[1][tid]) + (lw[2][tid] + lw[3][tid]);
        vec_out[(b * NBV + iter) * 64 + tid] = tot / lss[0];
    }
}

extern "C" void kernel_launch(void* const* d_in, const int* in_sizes, int n_in,
                              void* d_out, int out_size, void* d_ws, size_t ws_size,
                              hipStream_t stream) {
    const float* x = (const float*)d_in[0];           // [B,C,H,W] fp32
    const float* sc_in = (const float*)d_in[1];       // [B,N] fp32
    float* out = (float*)d_out;
    float* vec_out = out;                             // B*4*C
    float* sim_out = vec_out + (size_t)BB * NBV * CC; // B*4*N
    float* sel_out = sim_out + (size_t)BB * NBV * NN; // B*N

    float* ws = (float*)d_ws;
    float* score = ws;                                // B*N

    // primary layout
    float* bval = ws + (size_t)BB * NN;               // 2*PBP
    int* bidx = (int*)(bval + 2 * PBP);               // 2*PBP
    float* wpart = bval + 4 * PBP;                    // B*256*64
    float* sspart = wpart + (size_t)BB * 256 * 64;    // PBP
    float* rawbuf = sspart + PBP;                     // B*64
    float* xt = rawbuf + BB * 64;                     // B*N*64 (16B-aligned)
    size_t need = ((size_t)BB * NN + 4 * PBP + (size_t)BB * 256 * 64 + PBP
                   + BB * 64 + (size_t)BB * NN * 64) * sizeof(float);   // ~274 MB

    if (ws_size >= need) {
        k_transpose<<<dim3(1024, BB), 256, 0, stream>>>(x, xt);
        k_argmax1<<<dim3(256, BB), 256, 0, stream>>>(sc_in, bval, bidx, sel_out);
        for (int it = 0; it < NBV; it++) {
            const float* s_in = (it == 0) ? sc_in : score;
            k_pick<<<dim3(BB), 256, 0, stream>>>(xt, bval, bidx, rawbuf, it);
            k_iter_t<<<dim3(256, BB), 256, 0, stream>>>(xt, s_in, score, bval, bidx,
                                                        wpart, sspart, sim_out, rawbuf, it);
            k_fin<<<dim3(BB), 256, 0, stream>>>(wpart, sspart, vec_out, it);
        }
    } else {
        // fallback: round-3 proven c-major path
        float* fbval = ws + (size_t)BB * NN;          // 2*FBP
        int* fbidx = (int*)(fbval + 2 * FBP);         // 2*FBP
        float* fwpart = fbval + 4 * FBP;              // FBP*64
        float* fsspart = fwpart + (size_t)FBP * 64;   // FBP
        k_argmax1_fb<<<dim3(128, BB), 256, 0, stream>>>(sc_in, fbval, fbidx, sel_out);
        for (int it = 0; it < NBV; it++) {
            const float* s_in = (it == 0) ? sc_in : score;
            k_iter_fb<<<dim3(128, BB), 256, 0, stream>>>(x, s_in, score, fbval, fbidx,
                                                         fwpart, fsspart, sim_out, it);
            k_fin_fb<<<dim3(BB), 256, 0, stream>>>(fwpart, fsspart, vec_out, it);
        }
    }
}

// Round 6
// 789.217 us; speedup vs baseline: 1.2040x; 1.2040x over previous
//
#include <hip/hip_runtime.h>

#define BB 16
#define CC 64
#define NN 65536
#define NBV 4
#define NPB 64               // argmax/sum partials per batch: 64 blocks
#define BPP (BB * NPB)

// ws layout (fp32 elems): score B*N | bval 2*BPP | bidx 2*BPP (int) | wpart B*64*64 | sspart BPP | rawbuf B*64
//
// Round-6 schedule theory: read BW = f(resident waves x load-outstanding duty cycle).
// Same algorithm/traffic as the 548us round-0 kernel (c-major x, no transpose), but:
//  - 512 thr = 8 waves, 8 ch/wave, ~100 VGPR -> 16 waves/CU (2x round 0)
//  - register prefetch of group g+1 issued before group g's barrier/compute
//  - T4-style barriers: ds_write -> s_waitcnt lgkmcnt(0) -> raw s_barrier -> sched_barrier(0);
//    global loads are NEVER drained at barriers (vs __syncthreads' vmcnt(0) drain).

// Initial argmax over score_init (64 blocks/batch x 1024 scores) + zero selectedPos.
// Tie rule everywhere: larger value wins; equal -> smaller index (np.argmax = first max).
__global__ __launch_bounds__(256)
void k_argmax1(const float* __restrict__ sc_in,
               float* __restrict__ bval, int* __restrict__ bidx,
               float* __restrict__ sel_out) {
    int b = blockIdx.y, blk = blockIdx.x, tid = threadIdx.x;
    const float* s = sc_in + (size_t)b * NN + blk * 1024;
    float v = -1e30f; int vi = 0x7fffffff;
    #pragma unroll
    for (int k = 0; k < 4; k++) {
        int idx = k * 256 + tid;               // ascending per thread; strict > keeps earliest
        float xv = s[idx];
        if (xv > v) { v = xv; vi = blk * 1024 + idx; }
    }
    size_t gt = ((size_t)(b * 64 + blk)) * 256 + tid;   // 262144 threads x 4 = B*N
    #pragma unroll
    for (int k = 0; k < 4; k++) sel_out[gt + (size_t)k * 262144] = 0.f;
    __shared__ float sv[256]; __shared__ int si[256];
    sv[tid] = v; si[tid] = vi;
    __syncthreads();
    for (int st = 128; st > 0; st >>= 1) {
        if (tid < st) {
            float ov = sv[tid + st]; int oi = si[tid + st];
            if (ov > sv[tid] || (ov == sv[tid] && oi < si[tid])) { sv[tid] = ov; si[tid] = oi; }
        }
        __syncthreads();
    }
    if (tid == 0) { bval[b * 64 + blk] = sv[0]; bidx[b * 64 + blk] = si[0]; }
}

// Finalize argmax over 64 partials (one wave) + gather the selected pixel's 64 channels.
__global__ void k_pick(const float* __restrict__ x, const float* __restrict__ bval,
                       const int* __restrict__ bidx, float* __restrict__ rawbuf, int iter) {
    int b = blockIdx.x, lane = threadIdx.x;   // 64 threads = 1 wave
    int rb = (iter & 1) * BPP;
    float v = bval[rb + b * 64 + lane]; int vi = bidx[rb + b * 64 + lane];
    #pragma unroll
    for (int off = 32; off >= 1; off >>= 1) {
        float ov = __shfl_down(v, off, 64); int oi = __shfl_down(vi, off, 64);
        if (ov > v || (ov == v && oi < vi)) { v = ov; vi = oi; }
    }
    int ind = __shfl(vi, 0, 64);
    rawbuf[b * 64 + lane] = x[((size_t)(b * 64 + lane)) * NN + ind];
}

// Main per-iteration kernel. grid=(64,B), 512 thr = 8 waves; wave w owns channels 8w..8w+7.
// Lane owns 4 px (float4); 4 groups of 256 px. Per group: prefetch next group's 8 dwordx4
// (stay in flight across the barrier), d2 partial -> LDS dbuf, counted barrier, cross-wave
// sum -> sim4, 32 acc FMAs. Wave 0: sim store + sim-sum; wave 1: score I/O + fused stage-1
// argmax of the NEW score (ping-pong bval/bidx).
__global__ __launch_bounds__(512, 4)
void k_iter(const float* __restrict__ x, const float* __restrict__ score_in,
            float* __restrict__ score_out,
            float* __restrict__ bval, int* __restrict__ bidx,
            float* __restrict__ wpart, float* __restrict__ sspart,
            float* __restrict__ sim_out, const float* __restrict__ rawbuf, int iter) {
    int b = blockIdx.y, blk = blockIdx.x, tid = threadIdx.x;
    int lane = tid & 63, wv = tid >> 6;
    __shared__ __align__(16) float raw_s[64];
    __shared__ float4 d2p[2][8][64];

    int wb = ((iter & 1) ^ 1) * BPP;
    if (tid < 64) raw_s[tid] = rawbuf[b * 64 + tid];

    const float* xw = x + ((size_t)(b * 64 + wv * 8)) * NN;   // wave's channel base
    const size_t sb = (size_t)b * NN;
    const size_t simb = (size_t)(b * NBV + iter) * NN;
    const bool w0 = (wv == 0), w1 = (wv == 1), upd = (iter < 3);

    float acc[8];
    #pragma unroll
    for (int j = 0; j < 8; j++) acc[j] = 0.f;
    float ssacc = 0.f, smax = -1e30f; int smaxi = 0x7fffffff;

    // prefetch group 0 (before the prologue barrier)
    int nb0 = blk * 1024 + lane * 4;
    float4 xv0[8], xv1[8];
    #pragma unroll
    for (int j = 0; j < 8; j++) xv0[j] = *(const float4*)(xw + (size_t)j * NN + nb0);
    float4 sc0 = make_float4(0.f, 0.f, 0.f, 0.f), sc1 = sc0;
    if (w1 && upd) sc0 = *(const float4*)(score_in + sb + nb0);

    __syncthreads();                           // raw_s ready (full drain, once per kernel)
    float rloc[8];
    #pragma unroll
    for (int j = 0; j < 8; j++) rloc[j] = raw_s[wv * 8 + j];

    auto GROUP = [&](int g, float4 (&xc)[8], float4 (&xn)[8], float4& scc, float4& scn) {
        int ncur = blk * 1024 + g * 256 + lane * 4;
        if (g < 3) {                           // issue next group's loads NOW; they stay
            int nnx = ncur + 256;              // in flight across the counted barrier below
            #pragma unroll
            for (int j = 0; j < 8; j++) xn[j] = *(const float4*)(xw + (size_t)j * NN + nnx);
            if (w1 && upd) scn = *(const float4*)(score_in + sb + nnx);
        }
        float4 d2 = make_float4(0.f, 0.f, 0.f, 0.f);
        #pragma unroll
        for (int j = 0; j < 8; j++) {
            float r = rloc[j];
            float dx = xc[j].x - r, dy = xc[j].y - r, dz = xc[j].z - r, dw = xc[j].w - r;
            d2.x = fmaf(dx, dx, d2.x); d2.y = fmaf(dy, dy, d2.y);
            d2.z = fmaf(dz, dz, d2.z); d2.w = fmaf(dw, dw, d2.w);
        }
        d2p[g & 1][wv][lane] = d2;
        // counted barrier: wait only LDS (lgkmcnt), NOT the prefetch loads (vmcnt)
        asm volatile("s_waitcnt lgkmcnt(0)" ::: "memory");
        __builtin_amdgcn_s_barrier();
        __builtin_amdgcn_sched_barrier(0);
        float4 a = d2p[g & 1][0][lane];
        #pragma unroll
        for (int w = 1; w < 8; w++) {
            float4 t = d2p[g & 1][w][lane];
            a.x += t.x; a.y += t.y; a.z += t.z; a.w += t.w;
        }
        float4 sim;
        sim.x = expf(-sqrtf(fmaxf(a.x, 1e-12f)) * 0.05f);
        sim.y = expf(-sqrtf(fmaxf(a.y, 1e-12f)) * 0.05f);
        sim.z = expf(-sqrtf(fmaxf(a.z, 1e-12f)) * 0.05f);
        sim.w = expf(-sqrtf(fmaxf(a.w, 1e-12f)) * 0.05f);
        #pragma unroll
        for (int j = 0; j < 8; j++) {
            acc[j] = fmaf(sim.x, xc[j].x, acc[j]);
            acc[j] = fmaf(sim.y, xc[j].y, acc[j]);
            acc[j] = fmaf(sim.z, xc[j].z, acc[j]);
            acc[j] = fmaf(sim.w, xc[j].w, acc[j]);
        }
        if (w0) {
            ssacc += (sim.x + sim.y) + (sim.z + sim.w);
            *(float4*)(sim_out + simb + ncur) = sim;
        }
        if (w1 && upd) {
            float4 nc;
            nc.x = scc.x * (1.f - sim.x);
            nc.y = scc.y * (1.f - sim.y);
            nc.z = scc.z * (1.f - sim.z);
            nc.w = scc.w * (1.f - sim.w);
            *(float4*)(score_out + sb + ncur) = nc;
            // ascending n within lane & groups; strict > = first max
            if (nc.x > smax) { smax = nc.x; smaxi = ncur; }
            if (nc.y > smax) { smax = nc.y; smaxi = ncur + 1; }
            if (nc.z > smax) { smax = nc.z; smaxi = ncur + 2; }
            if (nc.w > smax) { smax = nc.w; smaxi = ncur + 3; }
        }
    };
    GROUP(0, xv0, xv1, sc0, sc1);
    GROUP(1, xv1, xv0, sc1, sc0);
    GROUP(2, xv0, xv1, sc0, sc1);
    GROUP(3, xv1, xv0, sc1, sc0);

    // epilogue: per-wave cross-lane reductions (8 channels -> 48 shuffles/wave)
    #pragma unroll
    for (int j = 0; j < 8; j++) {
        float v = acc[j];
        #pragma unroll
        for (int off = 32; off >= 1; off >>= 1) v += __shfl_down(v, off, 64);
        if (lane == 0) wpart[((size_t)(b * 64 + blk)) * 64 + wv * 8 + j] = v;
    }
    if (w0) {
        float v = ssacc;
        #pragma unroll
        for (int off = 32; off >= 1; off >>= 1) v += __shfl_down(v, off, 64);
        if (lane == 0) sspart[b * 64 + blk] = v;
    }
    if (w1 && upd) {
        #pragma unroll
        for (int off = 32; off >= 1; off >>= 1) {
            float ov = __shfl_down(smax, off, 64); int oi = __shfl_down(smaxi, off, 64);
            if (ov > smax || (ov == smax && oi < smaxi)) { smax = ov; smaxi = oi; }
        }
        if (lane == 0) { bval[wb + b * 64 + blk] = smax; bidx[wb + b * 64 + blk] = smaxi; }
    }
}

// Reduce 64 block-partials per batch. grid=(B), 256 thr: thread (c=tid&63, q=tid>>6)
// sums 16 blocks for channel c; wave 0 shuffle-reduces the 64 sim-sums.
__global__ __launch_bounds__(256)
void k_fin(const float* __restrict__ wpart, const float* __restrict__ sspart,
           float* __restrict__ vec_out, int iter) {
    int b = blockIdx.x, tid = threadIdx.x;
    int c = tid & 63, q = tid >> 6;
    __shared__ float lw[4][64];
    __shared__ float sstot;
    float w = 0.f;
    #pragma unroll
    for (int i = 0; i < 16; i++) w += wpart[((size_t)(b * 64 + q * 16 + i)) * 64 + c];
    lw[q][c] = w;
    if (tid < 64) {
        float s = sspart[b * 64 + tid];
        #pragma unroll
        for (int off = 32; off >= 1; off >>= 1) s += __shfl_down(s, off, 64);
        if (tid == 0) sstot = s;
    }
    __syncthreads();
    if (tid < 64) {
        float tot = (lw[0][tid] + lw[1][tid]) + (lw[2][tid] + lw[3][tid]);
        vec_out[(b * NBV + iter) * 64 + tid] = tot / sstot;
    }
}

extern "C" void kernel_launch(void* const* d_in, const int* in_sizes, int n_in,
                              void* d_out, int out_size, void* d_ws, size_t ws_size,
                              hipStream_t stream) {
    const float* x = (const float*)d_in[0];           // [B,C,H,W] fp32
    const float* sc_in = (const float*)d_in[1];       // [B,N] fp32
    float* out = (float*)d_out;
    float* vec_out = out;                             // B*4*C
    float* sim_out = vec_out + (size_t)BB * NBV * CC; // B*4*N
    float* sel_out = sim_out + (size_t)BB * NBV * NN; // B*N

    float* ws = (float*)d_ws;
    float* score = ws;                                // B*N
    float* bval = ws + (size_t)BB * NN;               // 2*BPP
    int* bidx = (int*)(bval + 2 * BPP);               // 2*BPP
    float* wpart = bval + 4 * BPP;                    // B*64*64
    float* sspart = wpart + (size_t)BB * 64 * 64;     // BPP
    float* rawbuf = sspart + BPP;                     // B*64

    k_argmax1<<<dim3(64, BB), 256, 0, stream>>>(sc_in, bval, bidx, sel_out);
    for (int it = 0; it < NBV; it++) {
        const float* s_in = (it == 0) ? sc_in : score;
        k_pick<<<dim3(BB), 64, 0, stream>>>(x, bval, bidx, rawbuf, it);
        k_iter<<<dim3(64, BB), 512, 0, stream>>>(x, s_in, score, bval, bidx,
                                                 wpart, sspart, sim_out, rawbuf, it);
        k_fin<<<dim3(BB), 256, 0, stream>>>(wpart, sspart, vec_out, it);
    }
}